// Round 6
// baseline (463.411 us; speedup 1.0000x reference)
//
#include <hip/hip_runtime.h>

// GAT node regressor: 3 GAT layers (HID=64, 4 heads x 16) + linear head.
// CSR-by-dst built once per call via bucketed counting sort, per-node ranges
// PADDED to x4 (pad edges -> phantom node n: als[n]=-1e30 so pe==0; xh row n
// zeroed). k_agg is BW-bound on random 256B xh gathers (~3.6TB/s effective,
// three structural variants identical) — main loop untouched. This round:
// the inter-layer 64x64 GEMM is ROW-LOCAL, so it is FUSED into k_agg's
// epilogue: the wave holds the full h-row (lane=col) for its 4 nodes ->
// stash in LDS -> fp32 dot vs pre-transposed W (16KB, L1-hot) -> next-layer
// xh/als/ald/mvec written directly. Deletes both k_mgemm<64> dispatches and
// the hbuf 25.6MB write+read round trip; layers 1-2 become pure fp32.
// Ping-pong A/B buffers avoid cross-block RAW races. Layer-0 GEMM (D=128,
// MFMA bf16 hi/lo) stays overlapped with the CSR build via k_mix1/k_mix2.

#define NBMAX 512    // max dst buckets (dst>>8); N=100K -> 391
#define SCHUNK 4096  // edges per bscatter block
#define BCAP 8192    // per-bucket LDS capacity in bfinal (avg 4096+pads)
#define PADSLACK 768 // max padding per bucket = 256 nodes * 3 slots

typedef __attribute__((ext_vector_type(8))) short bf16x8;
typedef __attribute__((ext_vector_type(4))) float f32x4;

__device__ inline unsigned short bf16_rtn(float x) {
    union { float f; unsigned u; } a; a.f = x;
    return (unsigned short)((a.u + 0x7FFFu + ((a.u >> 16) & 1u)) >> 16);
}
__device__ inline float bf16_to_f(unsigned short s) {
    union { unsigned u; float f; } b; b.u = ((unsigned)s) << 16;
    return b.f;
}

// ---- fused prep: blocks 0-3 pack w0 (bf16 hi/lo); 4 init; 5-6 transpose
// w1/w2 to fp32 [col][k] for the fused epilogue GEMM ----
__global__ __launch_bounds__(256) void k_prep(const float* __restrict__ w0, const float* __restrict__ w1,
                                              const float* __restrict__ w2,
                                              unsigned short* __restrict__ p0h, unsigned short* __restrict__ p0l,
                                              float* __restrict__ wt1, float* __restrict__ wt2,
                                              int* __restrict__ bhist,
                                              float* __restrict__ alsA, float* __restrict__ alsB,
                                              float* __restrict__ xhA, float* __restrict__ xhB, int n) {
    int bid = blockIdx.x, t = threadIdx.x;
    if (bid == 4) {  // init: zero bucket hist + phantom nodes (both buffers)
        bhist[t] = 0;
        bhist[t + 256] = 0;
        if (t < 4) {
            alsA[(size_t)n * 4 + t] = -1e30f;
            alsB[(size_t)n * 4 + t] = -1e30f;
        }
        if (t < 64) {
            xhA[(size_t)n * 64 + t] = 0.f;
            xhB[(size_t)n * 64 + t] = 0.f;
        }
        return;
    }
    if (bid >= 5) {  // transpose: wt[c*64+k] = W[k*64+c]
        const float* W = (bid == 5) ? w1 : w2;
        float* wt = (bid == 5) ? wt1 : wt2;
#pragma unroll
        for (int j = 0; j < 16; ++j) {
            int e = t * 16 + j;
            wt[e] = W[(size_t)(e & 63) * 64 + (e >> 6)];
        }
        return;
    }
    int idx = bid * 256 + t;  // [0,1024): pack w0, D=128: ko 0..15
    int ko = idx >> 6, nn = idx & 63;
#pragma unroll
    for (int j = 0; j < 8; ++j) {
        float w = w0[(size_t)(ko * 8 + j) * 64 + nn];
        unsigned short hb = bf16_rtn(w);
        p0h[(size_t)idx * 8 + j] = hb;
        p0l[(size_t)idx * 8 + j] = bf16_rtn(w - bf16_to_f(hb));
    }
}

__global__ __launch_bounds__(256) void k_bhist(const int* __restrict__ dst, int* __restrict__ bhist, int e) {
    __shared__ unsigned int h[NBMAX];
    int t = threadIdx.x;
    h[t] = 0;
    h[t + 256] = 0;
    __syncthreads();
    for (int i = blockIdx.x * 256 + t; i < e; i += gridDim.x * 256)
        atomicAdd(&h[dst[i] >> 8], 1u);
    __syncthreads();
    if (h[t]) atomicAdd(&bhist[t], (int)h[t]);
    if (h[t + 256]) atomicAdd(&bhist[t + 256], (int)h[t + 256]);
}

__global__ __launch_bounds__(512) void k_bscan(const int* __restrict__ bhist, int* __restrict__ boffs,
                                               int* __restrict__ bfill, int nb, int e) {
    __shared__ int s[NBMAX];
    int t = threadIdx.x;
    int v = (t < nb) ? bhist[t] : 0;
    s[t] = v;
    __syncthreads();
    for (int o = 1; o < 512; o <<= 1) {
        int add = (t >= o) ? s[t - o] : 0;
        __syncthreads();
        s[t] += add;
        __syncthreads();
    }
    boffs[t] = s[t] - v;  // exclusive
    if (t == 511) boffs[512] = s[511];
    bfill[t] = 0;
}

// ---- mgemm wave body (layer 0, D=128): 16 nodes x 64 cols ----
__device__ __forceinline__ void mgemm_wave128(const float* __restrict__ h,
                                              const unsigned short* __restrict__ wph,
                                              const unsigned short* __restrict__ wpl,
                                              const float* __restrict__ asrc, const float* __restrict__ adst,
                                              float* __restrict__ xh, float* __restrict__ als,
                                              float* __restrict__ ald, float* __restrict__ mvec,
                                              int m0, int lane, int n) {
    int quad = lane >> 4, l16 = lane & 15;
    int node_a = m0 + l16;
    int mm = min(node_a, n - 1);
    const float* hrow = h + (size_t)mm * 128 + quad * 8;

    f32x4 acc[4];
#pragma unroll
    for (int i = 0; i < 4; ++i) acc[i] = (f32x4){0.f, 0.f, 0.f, 0.f};

#pragma unroll
    for (int s = 0; s < 4; ++s) {
        float4 a0 = *(const float4*)(hrow + s * 32);
        float4 a1 = *(const float4*)(hrow + s * 32 + 4);
        float av[8] = {a0.x, a0.y, a0.z, a0.w, a1.x, a1.y, a1.z, a1.w};
        bf16x8 ahi, alo;
#pragma unroll
        for (int j = 0; j < 8; ++j) {
            unsigned short hb = bf16_rtn(av[j]);
            ahi[j] = (short)hb;
            alo[j] = (short)bf16_rtn(av[j] - bf16_to_f(hb));
        }
        const unsigned short* bbase = wph + ((size_t)((s * 4 + quad) * 64 + l16)) * 8;
        const unsigned short* bbasel = wpl + ((size_t)((s * 4 + quad) * 64 + l16)) * 8;
#pragma unroll
        for (int nt = 0; nt < 4; ++nt) {
            bf16x8 bhi = *(const bf16x8*)(bbase + (size_t)nt * 16 * 8);
            bf16x8 blo = *(const bf16x8*)(bbasel + (size_t)nt * 16 * 8);
            acc[nt] = __builtin_amdgcn_mfma_f32_16x16x32_bf16(ahi, bhi, acc[nt], 0, 0, 0);
            acc[nt] = __builtin_amdgcn_mfma_f32_16x16x32_bf16(ahi, blo, acc[nt], 0, 0, 0);
            acc[nt] = __builtin_amdgcn_mfma_f32_16x16x32_bf16(alo, bhi, acc[nt], 0, 0, 0);
        }
    }
#pragma unroll
    for (int nt = 0; nt < 4; ++nt) {
        float as_l = asrc[nt * 16 + l16];
        float ad_l = adst[nt * 16 + l16];
#pragma unroll
        for (int r = 0; r < 4; ++r) {
            int node = m0 + quad * 4 + r;
            float c = acc[nt][r];
            if (node < n) xh[(size_t)node * 64 + nt * 16 + l16] = c;
            float ps = c * as_l, pd = c * ad_l;
            ps += __shfl_xor(ps, 1, 64); pd += __shfl_xor(pd, 1, 64);
            ps += __shfl_xor(ps, 2, 64); pd += __shfl_xor(pd, 2, 64);
            ps += __shfl_xor(ps, 4, 64); pd += __shfl_xor(pd, 4, 64);
            ps += __shfl_xor(ps, 8, 64); pd += __shfl_xor(pd, 8, 64);
            if (l16 == 0 && node < n) {
                als[node * 4 + nt] = ps;
                ald[node * 4 + nt] = pd;
                float sm = ps + pd;
                mvec[node * 4 + nt] = sm >= 0.f ? sm : 0.2f * sm;
            }
        }
    }
}

// ---- k_mix1: bscatter (blocks [0,sb)) || layer-0 GEMM half 1 (8 waves) ----
__global__ __launch_bounds__(512) void k_mix1(const int* __restrict__ src, const int* __restrict__ dst,
                                              const int* __restrict__ boffs, int* __restrict__ bfill,
                                              unsigned int* __restrict__ edata, int e, int sb,
                                              const float* __restrict__ x,
                                              const unsigned short* __restrict__ p0h,
                                              const unsigned short* __restrict__ p0l,
                                              const float* __restrict__ asrc, const float* __restrict__ adst,
                                              float* __restrict__ xh, float* __restrict__ als,
                                              float* __restrict__ ald, float* __restrict__ mvec, int n) {
    __shared__ unsigned int hist[NBMAX];
    __shared__ unsigned int loc[NBMAX];
    __shared__ int gbase[NBMAX];
    __shared__ unsigned int stmp[NBMAX];
    __shared__ unsigned int sortbuf[SCHUNK];
    __shared__ int posbuf[SCHUNK];
    int t = threadIdx.x;
    if (blockIdx.x >= sb) {  // mgemm role
        int mblk = blockIdx.x - sb;
        int m0 = mblk * 128 + (t >> 6) * 16;
        mgemm_wave128(x, p0h, p0l, asrc, adst, xh, als, ald, mvec, m0, t & 63, n);
        return;
    }
    int i0 = blockIdx.x * SCHUNK;
    int cnt = min(SCHUNK, e - i0);
    hist[t] = 0;
    __syncthreads();
    for (int j = t; j < cnt; j += 512) atomicAdd(&hist[dst[i0 + j] >> 8], 1u);
    __syncthreads();
    unsigned int v = hist[t];
    stmp[t] = v;
    __syncthreads();
    for (int o = 1; o < 512; o <<= 1) {
        unsigned int add = (t >= o) ? stmp[t - o] : 0;
        __syncthreads();
        stmp[t] += add;
        __syncthreads();
    }
    loc[t] = stmp[t] - v;
    int gb = 0;
    if (v > 0) gb = atomicAdd(&bfill[t], (int)v);  // reserve contiguous run in bucket t
    gbase[t] = boffs[t] + gb - (int)loc[t];
    hist[t] = loc[t];  // cursor
    __syncthreads();
    for (int j = t; j < cnt; j += 512) {
        int d = dst[i0 + j];
        int s = src[i0 + j];
        int b = d >> 8;
        unsigned int p = atomicAdd(&hist[b], 1u);
        sortbuf[p] = (unsigned int)s | ((unsigned int)(d & 255) << 24);
        posbuf[p] = gbase[b] + (int)p;
    }
    __syncthreads();
    for (int j = t; j < cnt; j += 512) edata[posbuf[j]] = sortbuf[j];
}

// ---- k_mix2: bfinal (blocks [0,nb)) || layer-0 GEMM half 2 ----
__global__ __launch_bounds__(512) void k_mix2(const unsigned int* __restrict__ edata,
                                              const int* __restrict__ boffs, int* __restrict__ poffs,
                                              int* __restrict__ pend, int* __restrict__ ssrc,
                                              int n, int nb, int mg1,
                                              const float* __restrict__ x,
                                              const unsigned short* __restrict__ p0h,
                                              const unsigned short* __restrict__ p0l,
                                              const float* __restrict__ asrc, const float* __restrict__ adst,
                                              float* __restrict__ xh, float* __restrict__ als,
                                              float* __restrict__ ald, float* __restrict__ mvec) {
    __shared__ unsigned int hist[256];
    __shared__ unsigned int stmp[256];
    __shared__ unsigned int loc2[256];
    __shared__ unsigned int srcbuf[BCAP];
    int t = threadIdx.x;
    if (blockIdx.x >= nb) {  // mgemm role: second half of nodes
        int mblk = mg1 + (blockIdx.x - nb);
        int m0 = mblk * 128 + (t >> 6) * 16;
        mgemm_wave128(x, p0h, p0l, asrc, adst, xh, als, ald, mvec, m0, t & 63, n);
        return;
    }
    int b = blockIdx.x;
    int e0 = boffs[b], e1 = boffs[b + 1];
    int cnt = e1 - e0;
    int pb = e0 + b * PADSLACK;
    if (t < 256) hist[t] = 0;
    __syncthreads();
    for (int j = t; j < cnt; j += 512) atomicAdd(&hist[edata[e0 + j] >> 24], 1u);
    __syncthreads();
    unsigned int v = 0, v4 = 0;
    if (t < 256) {
        v = hist[t];
        v4 = (v + 3u) & ~3u;
        stmp[t] = v4;
    }
    __syncthreads();
    for (int o = 1; o < 256; o <<= 1) {
        unsigned int add = 0;
        if (t < 256 && t >= o) add = stmp[t - o];
        __syncthreads();
        if (t < 256) stmp[t] += add;
        __syncthreads();
    }
    int ptot = (int)stmp[255];
    if (t < 256) {
        loc2[t] = stmp[t] - v4;  // padded exclusive offset
        int node = b * 256 + t;
        if (node < n) {
            poffs[node] = pb + (int)loc2[t];
            pend[node] = pb + (int)(loc2[t] + v4);
        }
        hist[t] = loc2[t];  // cursor
    }
    __syncthreads();
    if (cnt + PADSLACK <= BCAP) {
        for (int j = t; j < cnt; j += 512) {
            unsigned int p = edata[e0 + j];
            unsigned int pos = atomicAdd(&hist[p >> 24], 1u);
            srcbuf[pos] = p & 0xFFFFFFu;
        }
        if (t < 256)
            for (unsigned int k = v; k < v4; ++k) srcbuf[loc2[t] + k] = (unsigned int)n;  // pads
        __syncthreads();
        for (int j = t; j < ptot; j += 512) ssrc[pb + j] = (int)srcbuf[j];
    } else {  // safety fallback (never hit for Poisson(4096) buckets)
        for (int j = t; j < cnt; j += 512) {
            unsigned int p = edata[e0 + j];
            unsigned int pos = atomicAdd(&hist[p >> 24], 1u);
            ssrc[pb + (int)pos] = (int)(p & 0xFFFFFFu);
        }
        if (t < 256)
            for (unsigned int k = v; k < v4; ++k) ssrc[pb + (int)(loc2[t] + k)] = n;
    }
}

__device__ inline float4 lrelu4(float4 v) {
    float4 r;
    r.x = v.x >= 0.f ? v.x : 0.2f * v.x;
    r.y = v.y >= 0.f ? v.y : 0.2f * v.y;
    r.z = v.z >= 0.f ? v.z : 0.2f * v.z;
    r.w = v.w >= 0.f ? v.w : 0.2f * v.w;
    return r;
}

// Aligned accumulate over [LO,HI) within chunk starting at s0; two fmac
// chains per node (ACCA/ACCB).
#define ACCUM(LO, HI, ACCA, ACCB, ZS)                                           \
    {                                                                           \
        int g_ = ((LO) - s0) >> 2, gb_ = ((HI) - s0) >> 2;                      \
        for (; g_ + 4 <= gb_; g_ += 4) {                                        \
            int4 uu0 = *(const int4*)&ub[g_ * 4];                               \
            int4 uu1 = *(const int4*)&ub[g_ * 4 + 4];                           \
            int4 uu2 = *(const int4*)&ub[g_ * 4 + 8];                           \
            int4 uu3 = *(const int4*)&ub[g_ * 4 + 12];                          \
            float4 pp0 = *(const float4*)&per[g_ * 4];                          \
            float4 pp1 = *(const float4*)&per[g_ * 4 + 4];                      \
            float4 pp2 = *(const float4*)&per[g_ * 4 + 8];                      \
            float4 pp3 = *(const float4*)&per[g_ * 4 + 12];                     \
            float x0 = *(const float*)(xl + (size_t)(unsigned)uu0.x);           \
            float x1 = *(const float*)(xl + (size_t)(unsigned)uu0.y);           \
            float x2 = *(const float*)(xl + (size_t)(unsigned)uu0.z);           \
            float x3 = *(const float*)(xl + (size_t)(unsigned)uu0.w);           \
            float x4 = *(const float*)(xl + (size_t)(unsigned)uu1.x);           \
            float x5 = *(const float*)(xl + (size_t)(unsigned)uu1.y);           \
            float x6 = *(const float*)(xl + (size_t)(unsigned)uu1.z);           \
            float x7 = *(const float*)(xl + (size_t)(unsigned)uu1.w);           \
            float x8 = *(const float*)(xl + (size_t)(unsigned)uu2.x);           \
            float x9 = *(const float*)(xl + (size_t)(unsigned)uu2.y);           \
            float xa = *(const float*)(xl + (size_t)(unsigned)uu2.z);           \
            float xb = *(const float*)(xl + (size_t)(unsigned)uu2.w);           \
            float xc = *(const float*)(xl + (size_t)(unsigned)uu3.x);           \
            float xd = *(const float*)(xl + (size_t)(unsigned)uu3.y);           \
            float xe = *(const float*)(xl + (size_t)(unsigned)uu3.z);           \
            float xf = *(const float*)(xl + (size_t)(unsigned)uu3.w);           \
            ZS += pp0.x + pp0.y + pp0.z + pp0.w;                                \
            ZS += pp1.x + pp1.y + pp1.z + pp1.w;                                \
            ZS += pp2.x + pp2.y + pp2.z + pp2.w;                                \
            ZS += pp3.x + pp3.y + pp3.z + pp3.w;                                \
            ACCA += pp0.x * x0; ACCB += pp0.y * x1;                             \
            ACCA += pp0.z * x2; ACCB += pp0.w * x3;                             \
            ACCA += pp1.x * x4; ACCB += pp1.y * x5;                             \
            ACCA += pp1.z * x6; ACCB += pp1.w * x7;                             \
            ACCA += pp2.x * x8; ACCB += pp2.y * x9;                             \
            ACCA += pp2.z * xa; ACCB += pp2.w * xb;                             \
            ACCA += pp3.x * xc; ACCB += pp3.y * xd;                             \
            ACCA += pp3.z * xe; ACCB += pp3.w * xf;                             \
        }                                                                       \
        for (; g_ < gb_; ++g_) {                                                \
            int4 uu = *(const int4*)&ub[g_ * 4];                                \
            float4 pp = *(const float4*)&per[g_ * 4];                           \
            float x0 = *(const float*)(xl + (size_t)(unsigned)uu.x);            \
            float x1 = *(const float*)(xl + (size_t)(unsigned)uu.y);            \
            float x2 = *(const float*)(xl + (size_t)(unsigned)uu.z);            \
            float x3 = *(const float*)(xl + (size_t)(unsigned)uu.w);            \
            ZS += pp.x + pp.y + pp.z + pp.w;                                    \
            ACCA += pp.x * x0; ACCB += pp.y * x1;                               \
            ACCA += pp.z * x2; ACCB += pp.w * x3;                               \
        }                                                                       \
    }

// 4 dst nodes per wave over padded CSR. If outw==null: fused next-layer GEMM
// epilogue (o rows -> LDS broadcast -> fp32 dot vs transposed W -> next
// xh/als/ald/mvec). Else: fused linear head.
__global__ __launch_bounds__(256) void k_agg(const float* __restrict__ xh,
                                             const float* __restrict__ als, const float* __restrict__ ald,
                                             const float* __restrict__ mvec,
                                             const int* __restrict__ poffs, const int* __restrict__ pend,
                                             const int* __restrict__ ssrc,
                                             const float* __restrict__ bias,
                                             const float* __restrict__ wtn, const float* __restrict__ asn,
                                             const float* __restrict__ adn,
                                             float* __restrict__ xho, float* __restrict__ also_,
                                             float* __restrict__ aldo, float* __restrict__ mveco,
                                             const float* __restrict__ outw, const float* __restrict__ outb,
                                             float* __restrict__ fout, int n) {
    __shared__ int s_u[4][64];
    __shared__ float s_pe[4][4][64];  // [wslot][head][edge]
    __shared__ float s_o[4][4][64];   // [wslot][node][col] for fused GEMM
    int wslot = threadIdx.x >> 6;
    int lane = threadIdx.x & 63;
    int w = (blockIdx.x * 256 + threadIdx.x) >> 6;
    int v0 = w << 2;
    if (v0 >= n) return;
    int head = lane >> 4;
    int* ub = s_u[wslot];
    float* per = s_pe[wslot][head];      // read row for my head
    float* pew = &s_pe[wslot][0][lane];  // write base, stride 64 per head

    int vlast = n - 1;
    int last = min(v0 + 3, vlast);
    int4 rr = *(const int4*)(poffs + v0);
    int e3 = pend[last];
    int r0 = rr.x;
    int r1 = (v0 + 1 <= last) ? rr.y : e3;
    int r2 = (v0 + 2 <= last) ? rr.z : e3;
    int r3 = (v0 + 3 <= last) ? rr.w : e3;

    const char* xl = (const char*)(xh + lane);  // lane column folded into base
    float acc0a = *(const float*)(xl + ((size_t)(unsigned)v0 << 8));  // self, pe=1
    float acc1a = *(const float*)(xl + ((size_t)(unsigned)min(v0 + 1, vlast) << 8));
    float acc2a = *(const float*)(xl + ((size_t)(unsigned)min(v0 + 2, vlast) << 8));
    float acc3a = *(const float*)(xl + ((size_t)(unsigned)min(v0 + 3, vlast) << 8));
    float acc0b = 0.f, acc1b = 0.f, acc2b = 0.f, acc3b = 0.f;
    float zs0 = 0.f, zs1 = 0.f, zs2 = 0.f, zs3 = 0.f;

    // prefetch chunk 0 (ssrc -> dependent als gather; ald/m by nid)
    int s0 = r0;
    int u_n = n;
    if (s0 < e3) {
        if (lane < e3 - s0) u_n = ssrc[s0 + lane];
    }
    float4 alu_n = *(const float4*)(als + 4 * (size_t)u_n);
    int e_n = s0 + lane;
    int nid_n = min(v0 + (e_n >= r1) + (e_n >= r2) + (e_n >= r3), vlast);
    float4 ald_n = *(const float4*)(ald + 4 * (size_t)nid_n);
    float4 m_n = *(const float4*)(mvec + 4 * (size_t)nid_n);

    while (s0 < e3) {
        int cnt = min(64, e3 - s0);
        float4 e4 = lrelu4(make_float4(alu_n.x + ald_n.x, alu_n.y + ald_n.y,
                                       alu_n.z + ald_n.z, alu_n.w + ald_n.w));
        float4 pe;
        pe.x = __expf(e4.x - m_n.x);
        pe.y = __expf(e4.y - m_n.y);
        pe.z = __expf(e4.z - m_n.z);
        pe.w = __expf(e4.w - m_n.w);
        ub[lane] = u_n << 8;  // row byte offset; pads point at phantom n
        pew[0] = pe.x;        // transposed stash: bank stride 64 -> 2-way, free
        pew[64] = pe.y;
        pew[128] = pe.z;
        pew[192] = pe.w;
        int s1 = s0 + 64;
        if (s1 < e3) {  // issue next chunk's loads before accumulate
            u_n = n;
            if (lane < e3 - s1) u_n = ssrc[s1 + lane];
            alu_n = *(const float4*)(als + 4 * (size_t)u_n);
            int e1 = s1 + lane;
            int nid1 = min(v0 + (e1 >= r1) + (e1 >= r2) + (e1 >= r3), vlast);
            ald_n = *(const float4*)(ald + 4 * (size_t)nid1);
            m_n = *(const float4*)(mvec + 4 * (size_t)nid1);
        }
        // same-wave LDS RAW (in-order DS unit), no barrier needed
        int lim = s0 + cnt;
        int hi0 = min(r1, lim);
        int lo1 = max(r1, s0), hi1 = min(r2, lim);
        int lo2 = max(r2, s0), hi2 = min(r3, lim);
        int lo3 = max(r3, s0);
        ACCUM(s0, hi0, acc0a, acc0b, zs0);
        ACCUM(lo1, hi1, acc1a, acc1b, zs1);
        ACCUM(lo2, hi2, acc2a, acc2b, zs2);
        ACCUM(lo3, lim, acc3a, acc3b, zs3);
        s0 = s1;
    }

    float bl = bias[lane];
    float o0 = fmaxf((acc0a + acc0b) / (1.f + zs0 + 1e-16f) + bl, 0.f);
    float o1 = fmaxf((acc1a + acc1b) / (1.f + zs1 + 1e-16f) + bl, 0.f);
    float o2 = fmaxf((acc2a + acc2b) / (1.f + zs2 + 1e-16f) + bl, 0.f);
    float o3 = fmaxf((acc3a + acc3b) / (1.f + zs3 + 1e-16f) + bl, 0.f);

    if (outw) {  // final layer: fused linear head
        float ow = outw[lane];
        float ob = outb[0];
        float t0 = o0 * ow, t1 = o1 * ow, t2 = o2 * ow, t3 = o3 * ow;
#pragma unroll
        for (int d = 32; d; d >>= 1) {
            t0 += __shfl_down(t0, d, 64);
            t1 += __shfl_down(t1, d, 64);
            t2 += __shfl_down(t2, d, 64);
            t3 += __shfl_down(t3, d, 64);
        }
        if (lane == 0) {
            fout[v0] = t0 + ob;
            if (v0 + 1 < n) fout[v0 + 1] = t1 + ob;
            if (v0 + 2 < n) fout[v0 + 2] = t2 + ob;
            if (v0 + 3 < n) fout[v0 + 3] = t3 + ob;
        }
        return;
    }

    // fused next-layer GEMM: h rows (lane=col) -> LDS, fp32 dot vs wt (L1-hot)
    float* ob = &s_o[wslot][0][0];
    ob[lane] = o0;
    ob[64 + lane] = o1;
    ob[128 + lane] = o2;
    ob[192 + lane] = o3;
    // same-wave LDS RAW, no barrier
    const float* wrow = wtn + (size_t)lane * 64;  // wt[c][k], row c contiguous
    float y0 = 0.f, y1 = 0.f, y2 = 0.f, y3 = 0.f;
#pragma unroll 4
    for (int k = 0; k < 64; k += 4) {
        float4 wv = *(const float4*)(wrow + k);
        float4 q0 = *(const float4*)(ob + k);
        float4 q1 = *(const float4*)(ob + 64 + k);
        float4 q2 = *(const float4*)(ob + 128 + k);
        float4 q3 = *(const float4*)(ob + 192 + k);
        y0 += q0.x * wv.x + q0.y * wv.y + q0.z * wv.z + q0.w * wv.w;
        y1 += q1.x * wv.x + q1.y * wv.y + q1.z * wv.z + q1.w * wv.w;
        y2 += q2.x * wv.x + q2.y * wv.y + q2.z * wv.z + q2.w * wv.w;
        y3 += q3.x * wv.x + q3.y * wv.y + q3.z * wv.z + q3.w * wv.w;
    }
    float as_l = asn[lane], ad_l = adn[lane];
#pragma unroll
    for (int nd = 0; nd < 4; ++nd) {
        int node = v0 + nd;
        if (node >= n) break;
        float y = nd == 0 ? y0 : nd == 1 ? y1 : nd == 2 ? y2 : y3;
        xho[(size_t)node * 64 + lane] = y;
        float ps = y * as_l, pd = y * ad_l;
        ps += __shfl_xor(ps, 1, 64); pd += __shfl_xor(pd, 1, 64);
        ps += __shfl_xor(ps, 2, 64); pd += __shfl_xor(pd, 2, 64);
        ps += __shfl_xor(ps, 4, 64); pd += __shfl_xor(pd, 4, 64);
        ps += __shfl_xor(ps, 8, 64); pd += __shfl_xor(pd, 8, 64);
        if ((lane & 15) == 0) {
            int h = lane >> 4;
            also_[node * 4 + h] = ps;
            aldo[node * 4 + h] = pd;
            float sm = ps + pd;
            mveco[node * 4 + h] = sm >= 0.f ? sm : 0.2f * sm;
        }
    }
}

extern "C" void kernel_launch(void* const* d_in, const int* in_sizes, int n_in,
                              void* d_out, int out_size, void* d_ws, size_t ws_size,
                              hipStream_t stream) {
    const float* x = (const float*)d_in[0];
    const int* ei = (const int*)d_in[1];
    const float* w[3] = {(const float*)d_in[2], (const float*)d_in[6], (const float*)d_in[10]};
    const float* as[3] = {(const float*)d_in[3], (const float*)d_in[7], (const float*)d_in[11]};
    const float* ad[3] = {(const float*)d_in[4], (const float*)d_in[8], (const float*)d_in[12]};
    const float* b[3] = {(const float*)d_in[5], (const float*)d_in[9], (const float*)d_in[13]};
    const float* outw = (const float*)d_in[14];
    const float* outb = (const float*)d_in[15];

    const int N = in_sizes[0] / 128;
    const int E = in_sizes[1] / 2;
    const int* src = ei;
    const int* dst = ei + E;
    const int NB = (N + 255) / 256;           // 391 <= NBMAX
    const int SB = (E + SCHUNK - 1) / SCHUNK; // 391
    const int GB128 = (N + 127) / 128;        // 782
    const int MG1 = (GB128 + 1) / 2;          // 391
    const int MG2 = GB128 - MG1;              // 391

    char* ws = (char*)d_ws;
    auto alloc = [&](size_t bytes) -> void* {
        void* p = (void*)ws;
        ws += (bytes + 255) & ~(size_t)255;
        return p;
    };
    int* bhist = (int*)alloc(NBMAX * 4);
    int* boffs = (int*)alloc((NBMAX + 1) * 4);
    int* bfill = (int*)alloc(NBMAX * 4);
    int* poffs = (int*)alloc((size_t)(N + 8) * 4);
    int* pend = (int*)alloc((size_t)N * 4);
    int* ssrc = (int*)alloc((size_t)(E + NBMAX * PADSLACK + 256) * 4);
    float* xhA = (float*)alloc((size_t)(N + 1) * 64 * 4);  // +1: phantom zero row
    float* xhB = (float*)alloc((size_t)(N + 1) * 64 * 4);
    float* alsA = (float*)alloc((size_t)(N + 1) * 4 * 4);  // +1: phantom -1e30
    float* alsB = (float*)alloc((size_t)(N + 1) * 4 * 4);
    float* aldA = (float*)alloc((size_t)N * 4 * 4);
    float* aldB = (float*)alloc((size_t)N * 4 * 4);
    float* mvecA = (float*)alloc((size_t)N * 4 * 4);
    float* mvecB = (float*)alloc((size_t)N * 4 * 4);
    unsigned short* p0h = (unsigned short*)alloc(8192 * 2);
    unsigned short* p0l = (unsigned short*)alloc(8192 * 2);
    float* wt1 = (float*)alloc(4096 * 4);
    float* wt2 = (float*)alloc(4096 * 4);
    // edata (E*4B = 6.4MB) aliases xhB rows [0, E/64): dead before agg0
    // writes xhB; phantom row n (offset 25.6MB) untouched by edata.
    unsigned int* edata = (unsigned int*)xhB;

    k_prep<<<7, 256, 0, stream>>>(w[0], w[1], w[2], p0h, p0l, wt1, wt2, bhist, alsA, alsB, xhA, xhB, N);
    k_bhist<<<256, 256, 0, stream>>>(dst, bhist, E);
    k_bscan<<<1, 512, 0, stream>>>(bhist, boffs, bfill, NB, E);
    // CSR scatter || layer-0 GEMM first half (independent workloads)
    k_mix1<<<SB + MG1, 512, 0, stream>>>(src, dst, boffs, bfill, edata, E, SB,
                                         x, p0h, p0l, as[0], ad[0], xhA, alsA, aldA, mvecA, N);
    // CSR finalize || layer-0 GEMM second half
    k_mix2<<<NB + MG2, 512, 0, stream>>>(edata, boffs, poffs, pend, ssrc, N, NB, MG1,
                                         x, p0h, p0l, as[0], ad[0], xhA, alsA, aldA, mvecA);

    const int ablocks = (N + 15) / 16;  // 4 nodes/wave, 4 waves/block

    // agg layer 0 + fused layer-1 GEMM (A -> B)
    k_agg<<<ablocks, 256, 0, stream>>>(xhA, alsA, aldA, mvecA, poffs, pend, ssrc, b[0],
                                       wt1, as[1], ad[1], xhB, alsB, aldB, mvecB,
                                       nullptr, nullptr, nullptr, N);
    // agg layer 1 + fused layer-2 GEMM (B -> A)
    k_agg<<<ablocks, 256, 0, stream>>>(xhB, alsB, aldB, mvecB, poffs, pend, ssrc, b[1],
                                       wt2, as[2], ad[2], xhA, alsA, aldA, mvecA,
                                       nullptr, nullptr, nullptr, N);
    // agg layer 2 + fused linear head
    k_agg<<<ablocks, 256, 0, stream>>>(xhA, alsA, aldA, mvecA, poffs, pend, ssrc, b[2],
                                       nullptr, nullptr, nullptr, nullptr, nullptr, nullptr, nullptr,
                                       outw, outb, (float*)d_out, N);
}

// Round 7
// 375.909 us; speedup vs baseline: 1.2328x; 1.2328x over previous
//
#include <hip/hip_runtime.h>

// GAT node regressor: 3 GAT layers (HID=64, 4 heads x 16) + linear head.
// CSR-by-dst built once per call via bucketed counting sort, per-node ranges
// PADDED to x4 (pad edges -> phantom node n: als[n]=-1e30 so pe==0; fp16 xh
// row n zeroed). k_agg is byte-limited on the per-edge row gather (3 rounds
// pinned at 230MB/3.6TB/s) -> this round HALVES gather bytes: GEMMs write a
// SECOND fp16 copy of xh (12.8MB); k_agg gathers neighbor rows from fp16
// (128B/edge) and reads the self row from the exact fp32 copy. Layer-0 GEMM
// (MFMA bf16 hi/lo) overlapped with CSR build via k_mix1/k_mix2 (R5).

#define NBMAX 512    // max dst buckets (dst>>8); N=100K -> 391
#define SCHUNK 4096  // edges per bscatter block
#define BCAP 8192    // per-bucket LDS capacity in bfinal (avg 4096+pads)
#define PADSLACK 768 // max padding per bucket = 256 nodes * 3 slots

typedef __attribute__((ext_vector_type(8))) short bf16x8;
typedef __attribute__((ext_vector_type(4))) float f32x4;
typedef _Float16 half_t;

__device__ inline unsigned short bf16_rtn(float x) {
    union { float f; unsigned u; } a; a.f = x;
    return (unsigned short)((a.u + 0x7FFFu + ((a.u >> 16) & 1u)) >> 16);
}
__device__ inline float bf16_to_f(unsigned short s) {
    union { unsigned u; float f; } b; b.u = ((unsigned)s) << 16;
    return b.f;
}

// ---- fused W-prep + init (9 blocks: 0-7 wprep, 8 init) ----
__global__ __launch_bounds__(256) void k_prep(const float* __restrict__ w0, const float* __restrict__ w1,
                                              const float* __restrict__ w2,
                                              unsigned short* __restrict__ p0h, unsigned short* __restrict__ p0l,
                                              unsigned short* __restrict__ p1h, unsigned short* __restrict__ p1l,
                                              unsigned short* __restrict__ p2h, unsigned short* __restrict__ p2l,
                                              int* __restrict__ bhist, float* __restrict__ als,
                                              half_t* __restrict__ xh16, int n) {
    int bid = blockIdx.x, t = threadIdx.x;
    if (bid == 8) {  // init: zero bucket hist + phantom node
        bhist[t] = 0;
        bhist[t + 256] = 0;
        if (t < 4) als[(size_t)n * 4 + t] = -1e30f;
        if (t < 64) xh16[(size_t)n * 64 + t] = (half_t)0.f;
        return;
    }
    int g = bid * 256 + t;
    const float* W;
    unsigned short *ph, *pl;
    int idx;
    if (g < 1024) { W = w0; ph = p0h; pl = p0l; idx = g; }          // D=128: ko 0..15
    else if (g < 1536) { W = w1; ph = p1h; pl = p1l; idx = g - 1024; }  // D=64: ko 0..7
    else if (g < 2048) { W = w2; ph = p2h; pl = p2l; idx = g - 1536; }
    else return;
    int ko = idx >> 6, nn = idx & 63;
#pragma unroll
    for (int j = 0; j < 8; ++j) {
        float w = W[(size_t)(ko * 8 + j) * 64 + nn];
        unsigned short hb = bf16_rtn(w);
        ph[(size_t)idx * 8 + j] = hb;
        pl[(size_t)idx * 8 + j] = bf16_rtn(w - bf16_to_f(hb));
    }
}

__global__ __launch_bounds__(256) void k_bhist(const int* __restrict__ dst, int* __restrict__ bhist, int e) {
    __shared__ unsigned int h[NBMAX];
    int t = threadIdx.x;
    h[t] = 0;
    h[t + 256] = 0;
    __syncthreads();
    for (int i = blockIdx.x * 256 + t; i < e; i += gridDim.x * 256)
        atomicAdd(&h[dst[i] >> 8], 1u);
    __syncthreads();
    if (h[t]) atomicAdd(&bhist[t], (int)h[t]);
    if (h[t + 256]) atomicAdd(&bhist[t + 256], (int)h[t + 256]);
}

__global__ __launch_bounds__(512) void k_bscan(const int* __restrict__ bhist, int* __restrict__ boffs,
                                               int* __restrict__ bfill, int nb, int e) {
    __shared__ int s[NBMAX];
    int t = threadIdx.x;
    int v = (t < nb) ? bhist[t] : 0;
    s[t] = v;
    __syncthreads();
    for (int o = 1; o < 512; o <<= 1) {
        int add = (t >= o) ? s[t - o] : 0;
        __syncthreads();
        s[t] += add;
        __syncthreads();
    }
    boffs[t] = s[t] - v;  // exclusive
    if (t == 511) boffs[512] = s[511];
    bfill[t] = 0;
}

// ---- mgemm wave body: 16 nodes x 64 cols, fused logits + softmax shift;
// writes fp32 xh AND fp16 xh16 (gather copy) ----
template <int D_IN>
__device__ __forceinline__ void mgemm_wave(const float* __restrict__ h,
                                           const unsigned short* __restrict__ wph,
                                           const unsigned short* __restrict__ wpl,
                                           const float* __restrict__ asrc, const float* __restrict__ adst,
                                           float* __restrict__ xh, half_t* __restrict__ xh16,
                                           float* __restrict__ als,
                                           float* __restrict__ ald, float* __restrict__ mvec,
                                           int m0, int lane, int n) {
    int quad = lane >> 4, l16 = lane & 15;
    int node_a = m0 + l16;
    int mm = min(node_a, n - 1);
    const float* hrow = h + (size_t)mm * D_IN + quad * 8;

    f32x4 acc[4];
#pragma unroll
    for (int i = 0; i < 4; ++i) acc[i] = (f32x4){0.f, 0.f, 0.f, 0.f};

    constexpr int KSTEPS = D_IN / 32;
#pragma unroll
    for (int s = 0; s < KSTEPS; ++s) {
        float4 a0 = *(const float4*)(hrow + s * 32);
        float4 a1 = *(const float4*)(hrow + s * 32 + 4);
        float av[8] = {a0.x, a0.y, a0.z, a0.w, a1.x, a1.y, a1.z, a1.w};
        bf16x8 ahi, alo;
#pragma unroll
        for (int j = 0; j < 8; ++j) {
            unsigned short hb = bf16_rtn(av[j]);
            ahi[j] = (short)hb;
            alo[j] = (short)bf16_rtn(av[j] - bf16_to_f(hb));
        }
        const unsigned short* bbase = wph + ((size_t)((s * 4 + quad) * 64 + l16)) * 8;
        const unsigned short* bbasel = wpl + ((size_t)((s * 4 + quad) * 64 + l16)) * 8;
#pragma unroll
        for (int nt = 0; nt < 4; ++nt) {
            bf16x8 bhi = *(const bf16x8*)(bbase + (size_t)nt * 16 * 8);
            bf16x8 blo = *(const bf16x8*)(bbasel + (size_t)nt * 16 * 8);
            acc[nt] = __builtin_amdgcn_mfma_f32_16x16x32_bf16(ahi, bhi, acc[nt], 0, 0, 0);
            acc[nt] = __builtin_amdgcn_mfma_f32_16x16x32_bf16(ahi, blo, acc[nt], 0, 0, 0);
            acc[nt] = __builtin_amdgcn_mfma_f32_16x16x32_bf16(alo, bhi, acc[nt], 0, 0, 0);
        }
    }
#pragma unroll
    for (int nt = 0; nt < 4; ++nt) {
        float as_l = asrc[nt * 16 + l16];
        float ad_l = adst[nt * 16 + l16];
#pragma unroll
        for (int r = 0; r < 4; ++r) {
            int node = m0 + quad * 4 + r;
            float c = acc[nt][r];
            if (node < n) {
                xh[(size_t)node * 64 + nt * 16 + l16] = c;
                xh16[(size_t)node * 64 + nt * 16 + l16] = (half_t)c;
            }
            float ps = c * as_l, pd = c * ad_l;
            ps += __shfl_xor(ps, 1, 64); pd += __shfl_xor(pd, 1, 64);
            ps += __shfl_xor(ps, 2, 64); pd += __shfl_xor(pd, 2, 64);
            ps += __shfl_xor(ps, 4, 64); pd += __shfl_xor(pd, 4, 64);
            ps += __shfl_xor(ps, 8, 64); pd += __shfl_xor(pd, 8, 64);
            if (l16 == 0 && node < n) {
                als[node * 4 + nt] = ps;
                ald[node * 4 + nt] = pd;
                float sm = ps + pd;
                mvec[node * 4 + nt] = sm >= 0.f ? sm : 0.2f * sm;
            }
        }
    }
}

// Standalone mgemm for layers 1-2 (D=64): 4 waves x 16 nodes.
template <int D_IN>
__global__ __launch_bounds__(256) void k_mgemm(const float* __restrict__ h,
                                               const unsigned short* __restrict__ wph,
                                               const unsigned short* __restrict__ wpl,
                                               const float* __restrict__ asrc, const float* __restrict__ adst,
                                               float* __restrict__ xh, half_t* __restrict__ xh16,
                                               float* __restrict__ als,
                                               float* __restrict__ ald, float* __restrict__ mvec, int n) {
    int t = threadIdx.x;
    int m0 = blockIdx.x * 64 + (t >> 6) * 16;
    mgemm_wave<D_IN>(h, wph, wpl, asrc, adst, xh, xh16, als, ald, mvec, m0, t & 63, n);
}

// ---- k_mix1: bscatter (blocks [0,sb)) || mgemm<128> half 1 (8 waves) ----
__global__ __launch_bounds__(512) void k_mix1(const int* __restrict__ src, const int* __restrict__ dst,
                                              const int* __restrict__ boffs, int* __restrict__ bfill,
                                              unsigned int* __restrict__ edata, int e, int sb,
                                              const float* __restrict__ x,
                                              const unsigned short* __restrict__ p0h,
                                              const unsigned short* __restrict__ p0l,
                                              const float* __restrict__ asrc, const float* __restrict__ adst,
                                              float* __restrict__ xh, half_t* __restrict__ xh16,
                                              float* __restrict__ als,
                                              float* __restrict__ ald, float* __restrict__ mvec, int n) {
    __shared__ unsigned int hist[NBMAX];
    __shared__ unsigned int loc[NBMAX];
    __shared__ int gbase[NBMAX];
    __shared__ unsigned int stmp[NBMAX];
    __shared__ unsigned int sortbuf[SCHUNK];
    __shared__ int posbuf[SCHUNK];
    int t = threadIdx.x;
    if (blockIdx.x >= sb) {  // mgemm role
        int mblk = blockIdx.x - sb;
        int m0 = mblk * 128 + (t >> 6) * 16;
        mgemm_wave<128>(x, p0h, p0l, asrc, adst, xh, xh16, als, ald, mvec, m0, t & 63, n);
        return;
    }
    int i0 = blockIdx.x * SCHUNK;
    int cnt = min(SCHUNK, e - i0);
    hist[t] = 0;
    __syncthreads();
    for (int j = t; j < cnt; j += 512) atomicAdd(&hist[dst[i0 + j] >> 8], 1u);
    __syncthreads();
    unsigned int v = hist[t];
    stmp[t] = v;
    __syncthreads();
    for (int o = 1; o < 512; o <<= 1) {
        unsigned int add = (t >= o) ? stmp[t - o] : 0;
        __syncthreads();
        stmp[t] += add;
        __syncthreads();
    }
    loc[t] = stmp[t] - v;
    int gb = 0;
    if (v > 0) gb = atomicAdd(&bfill[t], (int)v);  // reserve contiguous run in bucket t
    gbase[t] = boffs[t] + gb - (int)loc[t];
    hist[t] = loc[t];  // cursor
    __syncthreads();
    for (int j = t; j < cnt; j += 512) {
        int d = dst[i0 + j];
        int s = src[i0 + j];
        int b = d >> 8;
        unsigned int p = atomicAdd(&hist[b], 1u);
        sortbuf[p] = (unsigned int)s | ((unsigned int)(d & 255) << 24);
        posbuf[p] = gbase[b] + (int)p;
    }
    __syncthreads();
    for (int j = t; j < cnt; j += 512) edata[posbuf[j]] = sortbuf[j];
}

// ---- k_mix2: bfinal (blocks [0,nb)) || mgemm<128> half 2 ----
__global__ __launch_bounds__(512) void k_mix2(const unsigned int* __restrict__ edata,
                                              const int* __restrict__ boffs, int* __restrict__ poffs,
                                              int* __restrict__ pend, int* __restrict__ ssrc,
                                              int n, int nb, int mg1,
                                              const float* __restrict__ x,
                                              const unsigned short* __restrict__ p0h,
                                              const unsigned short* __restrict__ p0l,
                                              const float* __restrict__ asrc, const float* __restrict__ adst,
                                              float* __restrict__ xh, half_t* __restrict__ xh16,
                                              float* __restrict__ als,
                                              float* __restrict__ ald, float* __restrict__ mvec) {
    __shared__ unsigned int hist[256];
    __shared__ unsigned int stmp[256];
    __shared__ unsigned int loc2[256];
    __shared__ unsigned int srcbuf[BCAP];
    int t = threadIdx.x;
    if (blockIdx.x >= nb) {  // mgemm role: second half of nodes
        int mblk = mg1 + (blockIdx.x - nb);
        int m0 = mblk * 128 + (t >> 6) * 16;
        mgemm_wave<128>(x, p0h, p0l, asrc, adst, xh, xh16, als, ald, mvec, m0, t & 63, n);
        return;
    }
    int b = blockIdx.x;
    int e0 = boffs[b], e1 = boffs[b + 1];
    int cnt = e1 - e0;
    int pb = e0 + b * PADSLACK;
    if (t < 256) hist[t] = 0;
    __syncthreads();
    for (int j = t; j < cnt; j += 512) atomicAdd(&hist[edata[e0 + j] >> 24], 1u);
    __syncthreads();
    unsigned int v = 0, v4 = 0;
    if (t < 256) {
        v = hist[t];
        v4 = (v + 3u) & ~3u;
        stmp[t] = v4;
    }
    __syncthreads();
    for (int o = 1; o < 256; o <<= 1) {
        unsigned int add = 0;
        if (t < 256 && t >= o) add = stmp[t - o];
        __syncthreads();
        if (t < 256) stmp[t] += add;
        __syncthreads();
    }
    int ptot = (int)stmp[255];
    if (t < 256) {
        loc2[t] = stmp[t] - v4;  // padded exclusive offset
        int node = b * 256 + t;
        if (node < n) {
            poffs[node] = pb + (int)loc2[t];
            pend[node] = pb + (int)(loc2[t] + v4);
        }
        hist[t] = loc2[t];  // cursor
    }
    __syncthreads();
    if (cnt + PADSLACK <= BCAP) {
        for (int j = t; j < cnt; j += 512) {
            unsigned int p = edata[e0 + j];
            unsigned int pos = atomicAdd(&hist[p >> 24], 1u);
            srcbuf[pos] = p & 0xFFFFFFu;
        }
        if (t < 256)
            for (unsigned int k = v; k < v4; ++k) srcbuf[loc2[t] + k] = (unsigned int)n;  // pads
        __syncthreads();
        for (int j = t; j < ptot; j += 512) ssrc[pb + j] = (int)srcbuf[j];
    } else {  // safety fallback (never hit for Poisson(4096) buckets)
        for (int j = t; j < cnt; j += 512) {
            unsigned int p = edata[e0 + j];
            unsigned int pos = atomicAdd(&hist[p >> 24], 1u);
            ssrc[pb + (int)pos] = (int)(p & 0xFFFFFFu);
        }
        if (t < 256)
            for (unsigned int k = v; k < v4; ++k) ssrc[pb + (int)(loc2[t] + k)] = n;
    }
}

__device__ inline float4 lrelu4(float4 v) {
    float4 r;
    r.x = v.x >= 0.f ? v.x : 0.2f * v.x;
    r.y = v.y >= 0.f ? v.y : 0.2f * v.y;
    r.z = v.z >= 0.f ? v.z : 0.2f * v.z;
    r.w = v.w >= 0.f ? v.w : 0.2f * v.w;
    return r;
}

// Aligned accumulate over [LO,HI) within chunk starting at s0; fp16 row
// gathers (128B/edge), two fmac chains per node.
#define ACCUM(LO, HI, ACCA, ACCB, ZS)                                           \
    {                                                                           \
        int g_ = ((LO) - s0) >> 2, gb_ = ((HI) - s0) >> 2;                      \
        for (; g_ + 4 <= gb_; g_ += 4) {                                        \
            int4 uu0 = *(const int4*)&ub[g_ * 4];                               \
            int4 uu1 = *(const int4*)&ub[g_ * 4 + 4];                           \
            int4 uu2 = *(const int4*)&ub[g_ * 4 + 8];                           \
            int4 uu3 = *(const int4*)&ub[g_ * 4 + 12];                          \
            float4 pp0 = *(const float4*)&per[g_ * 4];                          \
            float4 pp1 = *(const float4*)&per[g_ * 4 + 4];                      \
            float4 pp2 = *(const float4*)&per[g_ * 4 + 8];                      \
            float4 pp3 = *(const float4*)&per[g_ * 4 + 12];                     \
            float x0 = (float)*(const half_t*)(xl + (size_t)(unsigned)uu0.x);   \
            float x1 = (float)*(const half_t*)(xl + (size_t)(unsigned)uu0.y);   \
            float x2 = (float)*(const half_t*)(xl + (size_t)(unsigned)uu0.z);   \
            float x3 = (float)*(const half_t*)(xl + (size_t)(unsigned)uu0.w);   \
            float x4 = (float)*(const half_t*)(xl + (size_t)(unsigned)uu1.x);   \
            float x5 = (float)*(const half_t*)(xl + (size_t)(unsigned)uu1.y);   \
            float x6 = (float)*(const half_t*)(xl + (size_t)(unsigned)uu1.z);   \
            float x7 = (float)*(const half_t*)(xl + (size_t)(unsigned)uu1.w);   \
            float x8 = (float)*(const half_t*)(xl + (size_t)(unsigned)uu2.x);   \
            float x9 = (float)*(const half_t*)(xl + (size_t)(unsigned)uu2.y);   \
            float xa = (float)*(const half_t*)(xl + (size_t)(unsigned)uu2.z);   \
            float xb = (float)*(const half_t*)(xl + (size_t)(unsigned)uu2.w);   \
            float xc = (float)*(const half_t*)(xl + (size_t)(unsigned)uu3.x);   \
            float xd = (float)*(const half_t*)(xl + (size_t)(unsigned)uu3.y);   \
            float xe = (float)*(const half_t*)(xl + (size_t)(unsigned)uu3.z);   \
            float xf = (float)*(const half_t*)(xl + (size_t)(unsigned)uu3.w);   \
            ZS += pp0.x + pp0.y + pp0.z + pp0.w;                                \
            ZS += pp1.x + pp1.y + pp1.z + pp1.w;                                \
            ZS += pp2.x + pp2.y + pp2.z + pp2.w;                                \
            ZS += pp3.x + pp3.y + pp3.z + pp3.w;                                \
            ACCA += pp0.x * x0; ACCB += pp0.y * x1;                             \
            ACCA += pp0.z * x2; ACCB += pp0.w * x3;                             \
            ACCA += pp1.x * x4; ACCB += pp1.y * x5;                             \
            ACCA += pp1.z * x6; ACCB += pp1.w * x7;                             \
            ACCA += pp2.x * x8; ACCB += pp2.y * x9;                             \
            ACCA += pp2.z * xa; ACCB += pp2.w * xb;                             \
            ACCA += pp3.x * xc; ACCB += pp3.y * xd;                             \
            ACCA += pp3.z * xe; ACCB += pp3.w * xf;                             \
        }                                                                       \
        for (; g_ < gb_; ++g_) {                                                \
            int4 uu = *(const int4*)&ub[g_ * 4];                                \
            float4 pp = *(const float4*)&per[g_ * 4];                           \
            float x0 = (float)*(const half_t*)(xl + (size_t)(unsigned)uu.x);    \
            float x1 = (float)*(const half_t*)(xl + (size_t)(unsigned)uu.y);    \
            float x2 = (float)*(const half_t*)(xl + (size_t)(unsigned)uu.z);    \
            float x3 = (float)*(const half_t*)(xl + (size_t)(unsigned)uu.w);    \
            ZS += pp.x + pp.y + pp.z + pp.w;                                    \
            ACCA += pp.x * x0; ACCB += pp.y * x1;                               \
            ACCA += pp.z * x2; ACCB += pp.w * x3;                               \
        }                                                                       \
    }

__global__ __launch_bounds__(256) void k_agg(const float* __restrict__ xh,
                                             const half_t* __restrict__ xh16,
                                             const float* __restrict__ als, const float* __restrict__ ald,
                                             const float* __restrict__ mvec,
                                             const int* __restrict__ poffs, const int* __restrict__ pend,
                                             const int* __restrict__ ssrc,
                                             const float* __restrict__ bias, float* __restrict__ hout,
                                             const float* __restrict__ outw, const float* __restrict__ outb,
                                             float* __restrict__ fout, int n) {
    __shared__ int s_u[4][64];
    __shared__ float s_pe[4][4][64];  // [wslot][head][edge]
    int wslot = threadIdx.x >> 6;
    int lane = threadIdx.x & 63;
    int w = (blockIdx.x * 256 + threadIdx.x) >> 6;
    int v0 = w << 2;
    if (v0 >= n) return;
    int head = lane >> 4;
    int* ub = s_u[wslot];
    float* per = s_pe[wslot][head];      // read row for my head
    float* pew = &s_pe[wslot][0][lane];  // write base, stride 64 per head

    int vlast = n - 1;
    int last = min(v0 + 3, vlast);
    int4 rr = *(const int4*)(poffs + v0);
    int e3 = pend[last];
    int r0 = rr.x;
    int r1 = (v0 + 1 <= last) ? rr.y : e3;
    int r2 = (v0 + 2 <= last) ? rr.z : e3;
    int r3 = (v0 + 3 <= last) ? rr.w : e3;

    const char* xl = (const char*)(xh16 + lane);  // lane column folded into base (fp16 rows)
    // self edges (pe = 1) from the EXACT fp32 copy
    float acc0a = xh[((size_t)(unsigned)v0 << 6) + lane];
    float acc1a = xh[((size_t)(unsigned)min(v0 + 1, vlast) << 6) + lane];
    float acc2a = xh[((size_t)(unsigned)min(v0 + 2, vlast) << 6) + lane];
    float acc3a = xh[((size_t)(unsigned)min(v0 + 3, vlast) << 6) + lane];
    float acc0b = 0.f, acc1b = 0.f, acc2b = 0.f, acc3b = 0.f;
    float zs0 = 0.f, zs1 = 0.f, zs2 = 0.f, zs3 = 0.f;

    // prefetch chunk 0 (ssrc -> dependent als gather; ald/m by nid)
    int s0 = r0;
    int u_n = n;
    if (s0 < e3) {
        if (lane < e3 - s0) u_n = ssrc[s0 + lane];
    }
    float4 alu_n = *(const float4*)(als + 4 * (size_t)u_n);
    int e_n = s0 + lane;
    int nid_n = min(v0 + (e_n >= r1) + (e_n >= r2) + (e_n >= r3), vlast);
    float4 ald_n = *(const float4*)(ald + 4 * (size_t)nid_n);
    float4 m_n = *(const float4*)(mvec + 4 * (size_t)nid_n);

    while (s0 < e3) {
        int cnt = min(64, e3 - s0);
        float4 e4 = lrelu4(make_float4(alu_n.x + ald_n.x, alu_n.y + ald_n.y,
                                       alu_n.z + ald_n.z, alu_n.w + ald_n.w));
        float4 pe;
        pe.x = __expf(e4.x - m_n.x);
        pe.y = __expf(e4.y - m_n.y);
        pe.z = __expf(e4.z - m_n.z);
        pe.w = __expf(e4.w - m_n.w);
        ub[lane] = u_n << 7;  // fp16 row byte offset; pads point at phantom n
        pew[0] = pe.x;        // transposed stash: bank stride 64 -> 2-way, free
        pew[64] = pe.y;
        pew[128] = pe.z;
        pew[192] = pe.w;
        int s1 = s0 + 64;
        if (s1 < e3) {  // issue next chunk's loads before accumulate
            u_n = n;
            if (lane < e3 - s1) u_n = ssrc[s1 + lane];
            alu_n = *(const float4*)(als + 4 * (size_t)u_n);
            int e1 = s1 + lane;
            int nid1 = min(v0 + (e1 >= r1) + (e1 >= r2) + (e1 >= r3), vlast);
            ald_n = *(const float4*)(ald + 4 * (size_t)nid1);
            m_n = *(const float4*)(mvec + 4 * (size_t)nid1);
        }
        // same-wave LDS RAW (in-order DS unit), no barrier needed
        int lim = s0 + cnt;
        int hi0 = min(r1, lim);
        int lo1 = max(r1, s0), hi1 = min(r2, lim);
        int lo2 = max(r2, s0), hi2 = min(r3, lim);
        int lo3 = max(r3, s0);
        ACCUM(s0, hi0, acc0a, acc0b, zs0);
        ACCUM(lo1, hi1, acc1a, acc1b, zs1);
        ACCUM(lo2, hi2, acc2a, acc2b, zs2);
        ACCUM(lo3, lim, acc3a, acc3b, zs3);
        s0 = s1;
    }

    float bl = bias[lane];
    float o0 = fmaxf((acc0a + acc0b) / (1.f + zs0 + 1e-16f) + bl, 0.f);
    float o1 = fmaxf((acc1a + acc1b) / (1.f + zs1 + 1e-16f) + bl, 0.f);
    float o2 = fmaxf((acc2a + acc2b) / (1.f + zs2 + 1e-16f) + bl, 0.f);
    float o3 = fmaxf((acc3a + acc3b) / (1.f + zs3 + 1e-16f) + bl, 0.f);
    if (outw) {
        float ow = outw[lane];
        float ob = outb[0];
        float t0 = o0 * ow, t1 = o1 * ow, t2 = o2 * ow, t3 = o3 * ow;
#pragma unroll
        for (int d = 32; d; d >>= 1) {
            t0 += __shfl_down(t0, d, 64);
            t1 += __shfl_down(t1, d, 64);
            t2 += __shfl_down(t2, d, 64);
            t3 += __shfl_down(t3, d, 64);
        }
        if (lane == 0) {
            fout[v0] = t0 + ob;
            if (v0 + 1 < n) fout[v0 + 1] = t1 + ob;
            if (v0 + 2 < n) fout[v0 + 2] = t2 + ob;
            if (v0 + 3 < n) fout[v0 + 3] = t3 + ob;
        }
    } else {
        hout[((size_t)v0 << 6) + lane] = o0;
        if (v0 + 1 < n) hout[((size_t)(v0 + 1) << 6) + lane] = o1;
        if (v0 + 2 < n) hout[((size_t)(v0 + 2) << 6) + lane] = o2;
        if (v0 + 3 < n) hout[((size_t)(v0 + 3) << 6) + lane] = o3;
    }
}

extern "C" void kernel_launch(void* const* d_in, const int* in_sizes, int n_in,
                              void* d_out, int out_size, void* d_ws, size_t ws_size,
                              hipStream_t stream) {
    const float* x = (const float*)d_in[0];
    const int* ei = (const int*)d_in[1];
    const float* w[3] = {(const float*)d_in[2], (const float*)d_in[6], (const float*)d_in[10]};
    const float* as[3] = {(const float*)d_in[3], (const float*)d_in[7], (const float*)d_in[11]};
    const float* ad[3] = {(const float*)d_in[4], (const float*)d_in[8], (const float*)d_in[12]};
    const float* b[3] = {(const float*)d_in[5], (const float*)d_in[9], (const float*)d_in[13]};
    const float* outw = (const float*)d_in[14];
    const float* outb = (const float*)d_in[15];

    const int N = in_sizes[0] / 128;
    const int E = in_sizes[1] / 2;
    const int* src = ei;
    const int* dst = ei + E;
    const int NB = (N + 255) / 256;           // 391 <= NBMAX
    const int SB = (E + SCHUNK - 1) / SCHUNK; // 391
    const int GB128 = (N + 127) / 128;        // 782
    const int MG1 = (GB128 + 1) / 2;          // 391
    const int MG2 = GB128 - MG1;              // 391

    char* ws = (char*)d_ws;
    auto alloc = [&](size_t bytes) -> void* {
        void* p = (void*)ws;
        ws += (bytes + 255) & ~(size_t)255;
        return p;
    };
    int* bhist = (int*)alloc(NBMAX * 4);
    int* boffs = (int*)alloc((NBMAX + 1) * 4);
    int* bfill = (int*)alloc(NBMAX * 4);
    int* poffs = (int*)alloc((size_t)(N + 8) * 4);
    int* pend = (int*)alloc((size_t)N * 4);
    int* ssrc = (int*)alloc((size_t)(E + NBMAX * PADSLACK + 256) * 4);
    unsigned int* edata = (unsigned int*)alloc((size_t)(E + 64) * 4);  // own slab
    float* xh = (float*)alloc((size_t)N * 64 * 4);
    half_t* xh16 = (half_t*)alloc((size_t)(N + 1) * 64 * 2);  // +1: phantom zero row
    float* hbuf = (float*)alloc((size_t)N * 64 * 4);
    float* als = (float*)alloc((size_t)(N + 1) * 4 * 4);  // +1: phantom -1e30
    float* ald = (float*)alloc((size_t)N * 4 * 4);
    float* mvec = (float*)alloc((size_t)N * 4 * 4);
    unsigned short* p0h = (unsigned short*)alloc(8192 * 2);
    unsigned short* p0l = (unsigned short*)alloc(8192 * 2);
    unsigned short* p1h = (unsigned short*)alloc(4096 * 2);
    unsigned short* p1l = (unsigned short*)alloc(4096 * 2);
    unsigned short* p2h = (unsigned short*)alloc(4096 * 2);
    unsigned short* p2l = (unsigned short*)alloc(4096 * 2);

    k_prep<<<9, 256, 0, stream>>>(w[0], w[1], w[2], p0h, p0l, p1h, p1l, p2h, p2l, bhist, als, xh16, N);
    k_bhist<<<256, 256, 0, stream>>>(dst, bhist, E);
    k_bscan<<<1, 512, 0, stream>>>(bhist, boffs, bfill, NB, E);
    // CSR scatter || layer-0 GEMM first half (independent workloads)
    k_mix1<<<SB + MG1, 512, 0, stream>>>(src, dst, boffs, bfill, edata, E, SB,
                                         x, p0h, p0l, as[0], ad[0], xh, xh16, als, ald, mvec, N);
    // CSR finalize || layer-0 GEMM second half
    k_mix2<<<NB + MG2, 512, 0, stream>>>(edata, boffs, poffs, pend, ssrc, N, NB, MG1,
                                         x, p0h, p0l, as[0], ad[0], xh, xh16, als, ald, mvec);

    const int gblocks = (N + 63) / 64;
    const int ablocks = (N + 15) / 16;  // 4 nodes/wave, 4 waves/block

    k_agg<<<ablocks, 256, 0, stream>>>(xh, xh16, als, ald, mvec, poffs, pend, ssrc, b[0], hbuf, nullptr, nullptr, nullptr, N);
    k_mgemm<64><<<gblocks, 256, 0, stream>>>(hbuf, p1h, p1l, as[1], ad[1], xh, xh16, als, ald, mvec, N);
    k_agg<<<ablocks, 256, 0, stream>>>(xh, xh16, als, ald, mvec, poffs, pend, ssrc, b[1], hbuf, nullptr, nullptr, nullptr, N);
    k_mgemm<64><<<gblocks, 256, 0, stream>>>(hbuf, p2h, p2l, as[2], ad[2], xh, xh16, als, ald, mvec, N);
    k_agg<<<ablocks, 256, 0, stream>>>(xh, xh16, als, ald, mvec, poffs, pend, ssrc, b[2], nullptr, outw, outb, (float*)d_out, N);
}

// Round 10
// 360.188 us; speedup vs baseline: 1.2866x; 1.0436x over previous
//
#include <hip/hip_runtime.h>

// GAT node regressor: 3 GAT layers (HID=64, 4 heads x 16) + linear head.
// CSR-by-dst via bucketed counting sort, per-node ranges PADDED to x4 (pads
// -> phantom node n: als[n]=-1e30 so pe==0; fp16 xh row n zeroed).
// Node features between layers stored ONCE, in fp16 (exact bf16 hi/lo
// re-split on GEMM input; single rounding event per layer): gathers
// 128B/row, GEMM A-reads and inter-layer stores halved vs fp32. k_agg
// gather path is the measured floor (R7: 54us, 125MB, 2.4TB/s L2-miss).
// Layer-0 GEMM (MFMA bf16 hi/lo from fp32 x) overlapped with CSR build via
// k_mix1/k_mix2. bhist fused into k_prep (zeroed by hipMemsetAsync).

#define NBMAX 512    // max dst buckets (dst>>8); N=100K -> 391
#define SCHUNK 4096  // edges per bscatter block
#define BCAP 8192    // per-bucket LDS capacity in bfinal (avg 4096+pads)
#define PADSLACK 768 // max padding per bucket = 256 nodes * 3 slots
#define NBH 256      // bhist role blocks inside k_prep

typedef __attribute__((ext_vector_type(8))) short bf16x8;
typedef __attribute__((ext_vector_type(4))) float f32x4;
typedef _Float16 half_t;
typedef __attribute__((ext_vector_type(8))) _Float16 half8;

__device__ inline unsigned short bf16_rtn(float x) {
    union { float f; unsigned u; } a; a.f = x;
    return (unsigned short)((a.u + 0x7FFFu + ((a.u >> 16) & 1u)) >> 16);
}
__device__ inline float bf16_to_f(unsigned short s) {
    union { unsigned u; float f; } b; b.u = ((unsigned)s) << 16;
    return b.f;
}

// ---- fused W-prep + phantom init + dst histogram (bhist pre-zeroed by
// hipMemsetAsync): blocks 0-7 wprep, 8 init, 9..9+NBH-1 bhist ----
__global__ __launch_bounds__(256) void k_prep(const float* __restrict__ w0, const float* __restrict__ w1,
                                              const float* __restrict__ w2,
                                              unsigned short* __restrict__ p0h, unsigned short* __restrict__ p0l,
                                              unsigned short* __restrict__ p1h, unsigned short* __restrict__ p1l,
                                              unsigned short* __restrict__ p2h, unsigned short* __restrict__ p2l,
                                              int* __restrict__ bhist, const int* __restrict__ dst, int e,
                                              float* __restrict__ als, half_t* __restrict__ xh16, int n) {
    __shared__ unsigned int h[NBMAX];
    int bid = blockIdx.x, t = threadIdx.x;
    if (bid == 8) {  // phantom node init
        if (t < 4) als[(size_t)n * 4 + t] = -1e30f;
        if (t < 64) xh16[(size_t)n * 64 + t] = (half_t)0.f;
        return;
    }
    if (bid >= 9) {  // bhist role (bhist already zeroed via memset)
        int bb = bid - 9;
        h[t] = 0;
        h[t + 256] = 0;
        __syncthreads();
        for (int i = bb * 256 + t; i < e; i += NBH * 256)
            atomicAdd(&h[dst[i] >> 8], 1u);
        __syncthreads();
        if (h[t]) atomicAdd(&bhist[t], (int)h[t]);
        if (h[t + 256]) atomicAdd(&bhist[t + 256], (int)h[t + 256]);
        return;
    }
    int g = bid * 256 + t;
    const float* W;
    unsigned short *ph, *pl;
    int idx;
    if (g < 1024) { W = w0; ph = p0h; pl = p0l; idx = g; }          // D=128: ko 0..15
    else if (g < 1536) { W = w1; ph = p1h; pl = p1l; idx = g - 1024; }  // D=64: ko 0..7
    else if (g < 2048) { W = w2; ph = p2h; pl = p2l; idx = g - 1536; }
    else return;
    int ko = idx >> 6, nn = idx & 63;
#pragma unroll
    for (int j = 0; j < 8; ++j) {
        float w = W[(size_t)(ko * 8 + j) * 64 + nn];
        unsigned short hb = bf16_rtn(w);
        ph[(size_t)idx * 8 + j] = hb;
        pl[(size_t)idx * 8 + j] = bf16_rtn(w - bf16_to_f(hb));
    }
}

__global__ __launch_bounds__(512) void k_bscan(const int* __restrict__ bhist, int* __restrict__ boffs,
                                               int* __restrict__ bfill, int nb, int e) {
    __shared__ int s[NBMAX];
    int t = threadIdx.x;
    int v = (t < nb) ? bhist[t] : 0;
    s[t] = v;
    __syncthreads();
    for (int o = 1; o < 512; o <<= 1) {
        int add = (t >= o) ? s[t - o] : 0;
        __syncthreads();
        s[t] += add;
        __syncthreads();
    }
    boffs[t] = s[t] - v;  // exclusive
    if (t == 511) boffs[512] = s[511];
    bfill[t] = 0;
}

// ---- mgemm wave body: 16 nodes x 64 cols, fused logits + softmax shift.
// HALF_IN: A rows are fp16 (exact under bf16 hi/lo re-split). Writes only
// the fp16 feature copy + fp32 logits (from the unrounded MFMA acc). ----
template <int D_IN, bool HALF_IN>
__device__ __forceinline__ void mgemm_wave(const void* __restrict__ hv,
                                           const unsigned short* __restrict__ wph,
                                           const unsigned short* __restrict__ wpl,
                                           const float* __restrict__ asrc, const float* __restrict__ adst,
                                           half_t* __restrict__ xh16, float* __restrict__ als,
                                           float* __restrict__ ald, float* __restrict__ mvec,
                                           int m0, int lane, int n) {
    int quad = lane >> 4, l16 = lane & 15;
    int node_a = m0 + l16;
    int mm = min(node_a, n - 1);

    f32x4 acc[4];
#pragma unroll
    for (int i = 0; i < 4; ++i) acc[i] = (f32x4){0.f, 0.f, 0.f, 0.f};

    constexpr int KSTEPS = D_IN / 32;
#pragma unroll
    for (int s = 0; s < KSTEPS; ++s) {
        float av[8];
        if constexpr (HALF_IN) {
            const half_t* hrow = (const half_t*)hv + (size_t)mm * D_IN + quad * 8;
            half8 hvv = *(const half8*)(hrow + s * 32);
#pragma unroll
            for (int j = 0; j < 8; ++j) av[j] = (float)hvv[j];
        } else {
            const float* hrow = (const float*)hv + (size_t)mm * D_IN + quad * 8;
            float4 a0 = *(const float4*)(hrow + s * 32);
            float4 a1 = *(const float4*)(hrow + s * 32 + 4);
            av[0] = a0.x; av[1] = a0.y; av[2] = a0.z; av[3] = a0.w;
            av[4] = a1.x; av[5] = a1.y; av[6] = a1.z; av[7] = a1.w;
        }
        bf16x8 ahi, alo;
#pragma unroll
        for (int j = 0; j < 8; ++j) {
            unsigned short hb = bf16_rtn(av[j]);
            ahi[j] = (short)hb;
            alo[j] = (short)bf16_rtn(av[j] - bf16_to_f(hb));
        }
        const unsigned short* bbase = wph + ((size_t)((s * 4 + quad) * 64 + l16)) * 8;
        const unsigned short* bbasel = wpl + ((size_t)((s * 4 + quad) * 64 + l16)) * 8;
#pragma unroll
        for (int nt = 0; nt < 4; ++nt) {
            bf16x8 bhi = *(const bf16x8*)(bbase + (size_t)nt * 16 * 8);
            bf16x8 blo = *(const bf16x8*)(bbasel + (size_t)nt * 16 * 8);
            acc[nt] = __builtin_amdgcn_mfma_f32_16x16x32_bf16(ahi, bhi, acc[nt], 0, 0, 0);
            acc[nt] = __builtin_amdgcn_mfma_f32_16x16x32_bf16(ahi, blo, acc[nt], 0, 0, 0);
            acc[nt] = __builtin_amdgcn_mfma_f32_16x16x32_bf16(alo, bhi, acc[nt], 0, 0, 0);
        }
    }
#pragma unroll
    for (int nt = 0; nt < 4; ++nt) {
        float as_l = asrc[nt * 16 + l16];
        float ad_l = adst[nt * 16 + l16];
#pragma unroll
        for (int r = 0; r < 4; ++r) {
            int node = m0 + quad * 4 + r;
            float c = acc[nt][r];
            if (node < n) xh16[(size_t)node * 64 + nt * 16 + l16] = (half_t)c;
            float ps = c * as_l, pd = c * ad_l;
            ps += __shfl_xor(ps, 1, 64); pd += __shfl_xor(pd, 1, 64);
            ps += __shfl_xor(ps, 2, 64); pd += __shfl_xor(pd, 2, 64);
            ps += __shfl_xor(ps, 4, 64); pd += __shfl_xor(pd, 4, 64);
            ps += __shfl_xor(ps, 8, 64); pd += __shfl_xor(pd, 8, 64);
            if (l16 == 0 && node < n) {
                als[node * 4 + nt] = ps;
                ald[node * 4 + nt] = pd;
                float sm = ps + pd;
                mvec[node * 4 + nt] = sm >= 0.f ? sm : 0.2f * sm;
            }
        }
    }
}

// Standalone mgemm for layers 1-2 (D=64, fp16 input): 4 waves x 16 nodes.
__global__ __launch_bounds__(256) void k_mgemm64(const half_t* __restrict__ h,
                                                 const unsigned short* __restrict__ wph,
                                                 const unsigned short* __restrict__ wpl,
                                                 const float* __restrict__ asrc, const float* __restrict__ adst,
                                                 half_t* __restrict__ xh16, float* __restrict__ als,
                                                 float* __restrict__ ald, float* __restrict__ mvec, int n) {
    int t = threadIdx.x;
    int m0 = blockIdx.x * 64 + (t >> 6) * 16;
    mgemm_wave<64, true>(h, wph, wpl, asrc, adst, xh16, als, ald, mvec, m0, t & 63, n);
}

// ---- k_mix1: bscatter (blocks [0,sb)) || layer-0 GEMM half 1 (8 waves) ----
__global__ __launch_bounds__(512) void k_mix1(const int* __restrict__ src, const int* __restrict__ dst,
                                              const int* __restrict__ boffs, int* __restrict__ bfill,
                                              unsigned int* __restrict__ edata, int e, int sb,
                                              const float* __restrict__ x,
                                              const unsigned short* __restrict__ p0h,
                                              const unsigned short* __restrict__ p0l,
                                              const float* __restrict__ asrc, const float* __restrict__ adst,
                                              half_t* __restrict__ xh16, float* __restrict__ als,
                                              float* __restrict__ ald, float* __restrict__ mvec, int n) {
    __shared__ unsigned int hist[NBMAX];
    __shared__ unsigned int loc[NBMAX];
    __shared__ int gbase[NBMAX];
    __shared__ unsigned int stmp[NBMAX];
    __shared__ unsigned int sortbuf[SCHUNK];
    __shared__ int posbuf[SCHUNK];
    int t = threadIdx.x;
    if (blockIdx.x >= sb) {  // mgemm role
        int mblk = blockIdx.x - sb;
        int m0 = mblk * 128 + (t >> 6) * 16;
        mgemm_wave<128, false>(x, p0h, p0l, asrc, adst, xh16, als, ald, mvec, m0, t & 63, n);
        return;
    }
    int i0 = blockIdx.x * SCHUNK;
    int cnt = min(SCHUNK, e - i0);
    hist[t] = 0;
    __syncthreads();
    for (int j = t; j < cnt; j += 512) atomicAdd(&hist[dst[i0 + j] >> 8], 1u);
    __syncthreads();
    unsigned int v = hist[t];
    stmp[t] = v;
    __syncthreads();
    for (int o = 1; o < 512; o <<= 1) {
        unsigned int add = (t >= o) ? stmp[t - o] : 0;
        __syncthreads();
        stmp[t] += add;
        __syncthreads();
    }
    loc[t] = stmp[t] - v;
    int gb = 0;
    if (v > 0) gb = atomicAdd(&bfill[t], (int)v);  // reserve contiguous run in bucket t
    gbase[t] = boffs[t] + gb - (int)loc[t];
    hist[t] = loc[t];  // cursor
    __syncthreads();
    for (int j = t; j < cnt; j += 512) {
        int d = dst[i0 + j];
        int s = src[i0 + j];
        int b = d >> 8;
        unsigned int p = atomicAdd(&hist[b], 1u);
        sortbuf[p] = (unsigned int)s | ((unsigned int)(d & 255) << 24);
        posbuf[p] = gbase[b] + (int)p;
    }
    __syncthreads();
    for (int j = t; j < cnt; j += 512) edata[posbuf[j]] = sortbuf[j];
}

// ---- k_mix2: bfinal (blocks [0,nb)) || layer-0 GEMM half 2 ----
__global__ __launch_bounds__(512) void k_mix2(const unsigned int* __restrict__ edata,
                                              const int* __restrict__ boffs, int* __restrict__ poffs,
                                              int* __restrict__ pend, int* __restrict__ ssrc,
                                              int n, int nb, int mg1,
                                              const float* __restrict__ x,
                                              const unsigned short* __restrict__ p0h,
                                              const unsigned short* __restrict__ p0l,
                                              const float* __restrict__ asrc, const float* __restrict__ adst,
                                              half_t* __restrict__ xh16, float* __restrict__ als,
                                              float* __restrict__ ald, float* __restrict__ mvec) {
    __shared__ unsigned int hist[256];
    __shared__ unsigned int stmp[256];
    __shared__ unsigned int loc2[256];
    __shared__ unsigned int srcbuf[BCAP];
    int t = threadIdx.x;
    if (blockIdx.x >= nb) {  // mgemm role: second half of nodes
        int mblk = mg1 + (blockIdx.x - nb);
        int m0 = mblk * 128 + (t >> 6) * 16;
        mgemm_wave<128, false>(x, p0h, p0l, asrc, adst, xh16, als, ald, mvec, m0, t & 63, n);
        return;
    }
    int b = blockIdx.x;
    int e0 = boffs[b], e1 = boffs[b + 1];
    int cnt = e1 - e0;
    int pb = e0 + b * PADSLACK;
    if (t < 256) hist[t] = 0;
    __syncthreads();
    for (int j = t; j < cnt; j += 512) atomicAdd(&hist[edata[e0 + j] >> 24], 1u);
    __syncthreads();
    unsigned int v = 0, v4 = 0;
    if (t < 256) {
        v = hist[t];
        v4 = (v + 3u) & ~3u;
        stmp[t] = v4;
    }
    __syncthreads();
    for (int o = 1; o < 256; o <<= 1) {
        unsigned int add = 0;
        if (t < 256 && t >= o) add = stmp[t - o];
        __syncthreads();
        if (t < 256) stmp[t] += add;
        __syncthreads();
    }
    int ptot = (int)stmp[255];
    if (t < 256) {
        loc2[t] = stmp[t] - v4;  // padded exclusive offset
        int node = b * 256 + t;
        if (node < n) {
            poffs[node] = pb + (int)loc2[t];
            pend[node] = pb + (int)(loc2[t] + v4);
        }
        hist[t] = loc2[t];  // cursor
    }
    __syncthreads();
    if (cnt + PADSLACK <= BCAP) {
        for (int j = t; j < cnt; j += 512) {
            unsigned int p = edata[e0 + j];
            unsigned int pos = atomicAdd(&hist[p >> 24], 1u);
            srcbuf[pos] = p & 0xFFFFFFu;
        }
        if (t < 256)
            for (unsigned int k = v; k < v4; ++k) srcbuf[loc2[t] + k] = (unsigned int)n;  // pads
        __syncthreads();
        for (int j = t; j < ptot; j += 512) ssrc[pb + j] = (int)srcbuf[j];
    } else {  // safety fallback (never hit for Poisson(4096) buckets)
        for (int j = t; j < cnt; j += 512) {
            unsigned int p = edata[e0 + j];
            unsigned int pos = atomicAdd(&hist[p >> 24], 1u);
            ssrc[pb + (int)pos] = (int)(p & 0xFFFFFFu);
        }
        if (t < 256)
            for (unsigned int k = v; k < v4; ++k) ssrc[pb + (int)(loc2[t] + k)] = n;
    }
}

__device__ inline float4 lrelu4(float4 v) {
    float4 r;
    r.x = v.x >= 0.f ? v.x : 0.2f * v.x;
    r.y = v.y >= 0.f ? v.y : 0.2f * v.y;
    r.z = v.z >= 0.f ? v.z : 0.2f * v.z;
    r.w = v.w >= 0.f ? v.w : 0.2f * v.w;
    return r;
}

// Aligned accumulate over [LO,HI) within chunk starting at s0; fp16 row
// gathers (128B/edge), two fmac chains per node.
#define ACCUM(LO, HI, ACCA, ACCB, ZS)                                           \
    {                                                                           \
        int g_ = ((LO) - s0) >> 2, gb_ = ((HI) - s0) >> 2;                      \
        for (; g_ + 4 <= gb_; g_ += 4) {                                        \
            int4 uu0 = *(const int4*)&ub[g_ * 4];                               \
            int4 uu1 = *(const int4*)&ub[g_ * 4 + 4];                           \
            int4 uu2 = *(const int4*)&ub[g_ * 4 + 8];                           \
            int4 uu3 = *(const int4*)&ub[g_ * 4 + 12];                          \
            float4 pp0 = *(const float4*)&per[g_ * 4];                          \
            float4 pp1 = *(const float4*)&per[g_ * 4 + 4];                      \
            float4 pp2 = *(const float4*)&per[g_ * 4 + 8];                      \
            float4 pp3 = *(const float4*)&per[g_ * 4 + 12];                     \
            float x0 = (float)*(const half_t*)(xl + (size_t)(unsigned)uu0.x);   \
            float x1 = (float)*(const half_t*)(xl + (size_t)(unsigned)uu0.y);   \
            float x2 = (float)*(const half_t*)(xl + (size_t)(unsigned)uu0.z);   \
            float x3 = (float)*(const half_t*)(xl + (size_t)(unsigned)uu0.w);   \
            float x4 = (float)*(const half_t*)(xl + (size_t)(unsigned)uu1.x);   \
            float x5 = (float)*(const half_t*)(xl + (size_t)(unsigned)uu1.y);   \
            float x6 = (float)*(const half_t*)(xl + (size_t)(unsigned)uu1.z);   \
            float x7 = (float)*(const half_t*)(xl + (size_t)(unsigned)uu1.w);   \
            float x8 = (float)*(const half_t*)(xl + (size_t)(unsigned)uu2.x);   \
            float x9 = (float)*(const half_t*)(xl + (size_t)(unsigned)uu2.y);   \
            float xa = (float)*(const half_t*)(xl + (size_t)(unsigned)uu2.z);   \
            float xb = (float)*(const half_t*)(xl + (size_t)(unsigned)uu2.w);   \
            float xc = (float)*(const half_t*)(xl + (size_t)(unsigned)uu3.x);   \
            float xd = (float)*(const half_t*)(xl + (size_t)(unsigned)uu3.y);   \
            float xe = (float)*(const half_t*)(xl + (size_t)(unsigned)uu3.z);   \
            float xf = (float)*(const half_t*)(xl + (size_t)(unsigned)uu3.w);   \
            ZS += pp0.x + pp0.y + pp0.z + pp0.w;                                \
            ZS += pp1.x + pp1.y + pp1.z + pp1.w;                                \
            ZS += pp2.x + pp2.y + pp2.z + pp2.w;                                \
            ZS += pp3.x + pp3.y + pp3.z + pp3.w;                                \
            ACCA += pp0.x * x0; ACCB += pp0.y * x1;                             \
            ACCA += pp0.z * x2; ACCB += pp0.w * x3;                             \
            ACCA += pp1.x * x4; ACCB += pp1.y * x5;                             \
            ACCA += pp1.z * x6; ACCB += pp1.w * x7;                             \
            ACCA += pp2.x * x8; ACCB += pp2.y * x9;                             \
            ACCA += pp2.z * xa; ACCB += pp2.w * xb;                             \
            ACCA += pp3.x * xc; ACCB += pp3.y * xd;                             \
            ACCA += pp3.z * xe; ACCB += pp3.w * xf;                             \
        }                                                                       \
        for (; g_ < gb_; ++g_) {                                                \
            int4 uu = *(const int4*)&ub[g_ * 4];                                \
            float4 pp = *(const float4*)&per[g_ * 4];                           \
            float x0 = (float)*(const half_t*)(xl + (size_t)(unsigned)uu.x);    \
            float x1 = (float)*(const half_t*)(xl + (size_t)(unsigned)uu.y);    \
            float x2 = (float)*(const half_t*)(xl + (size_t)(unsigned)uu.z);    \
            float x3 = (float)*(const half_t*)(xl + (size_t)(unsigned)uu.w);    \
            ZS += pp.x + pp.y + pp.z + pp.w;                                    \
            ACCA += pp.x * x0; ACCB += pp.y * x1;                               \
            ACCA += pp.z * x2; ACCB += pp.w * x3;                               \
        }                                                                       \
    }

__global__ __launch_bounds__(256) void k_agg(const half_t* __restrict__ xh16,
                                             const float* __restrict__ als, const float* __restrict__ ald,
                                             const float* __restrict__ mvec,
                                             const int* __restrict__ poffs, const int* __restrict__ pend,
                                             const int* __restrict__ ssrc,
                                             const float* __restrict__ bias, half_t* __restrict__ hout,
                                             const float* __restrict__ outw, const float* __restrict__ outb,
                                             float* __restrict__ fout, int n) {
    __shared__ int s_u[4][64];
    __shared__ float s_pe[4][4][64];  // [wslot][head][edge]
    int wslot = threadIdx.x >> 6;
    int lane = threadIdx.x & 63;
    int w = (blockIdx.x * 256 + threadIdx.x) >> 6;
    int v0 = w << 2;
    if (v0 >= n) return;
    int head = lane >> 4;
    int* ub = s_u[wslot];
    float* per = s_pe[wslot][head];      // read row for my head
    float* pew = &s_pe[wslot][0][lane];  // write base, stride 64 per head

    int vlast = n - 1;
    int last = min(v0 + 3, vlast);
    int4 rr = *(const int4*)(poffs + v0);
    int e3 = pend[last];
    int r0 = rr.x;
    int r1 = (v0 + 1 <= last) ? rr.y : e3;
    int r2 = (v0 + 2 <= last) ? rr.z : e3;
    int r3 = (v0 + 3 <= last) ? rr.w : e3;

    const char* xl = (const char*)(xh16 + lane);  // lane column folded into base
    // self edges (pe = 1), fp16 feature copy
    float acc0a = (float)xh16[((size_t)(unsigned)v0 << 6) + lane];
    float acc1a = (float)xh16[((size_t)(unsigned)min(v0 + 1, vlast) << 6) + lane];
    float acc2a = (float)xh16[((size_t)(unsigned)min(v0 + 2, vlast) << 6) + lane];
    float acc3a = (float)xh16[((size_t)(unsigned)min(v0 + 3, vlast) << 6) + lane];
    float acc0b = 0.f, acc1b = 0.f, acc2b = 0.f, acc3b = 0.f;
    float zs0 = 0.f, zs1 = 0.f, zs2 = 0.f, zs3 = 0.f;

    // prefetch chunk 0 (ssrc -> dependent als gather; ald/m by nid)
    int s0 = r0;
    int u_n = n;
    if (s0 < e3) {
        if (lane < e3 - s0) u_n = ssrc[s0 + lane];
    }
    float4 alu_n = *(const float4*)(als + 4 * (size_t)u_n);
    int e_n = s0 + lane;
    int nid_n = min(v0 + (e_n >= r1) + (e_n >= r2) + (e_n >= r3), vlast);
    float4 ald_n = *(const float4*)(ald + 4 * (size_t)nid_n);
    float4 m_n = *(const float4*)(mvec + 4 * (size_t)nid_n);

    while (s0 < e3) {
        int cnt = min(64, e3 - s0);
        float4 e4 = lrelu4(make_float4(alu_n.x + ald_n.x, alu_n.y + ald_n.y,
                                       alu_n.z + ald_n.z, alu_n.w + ald_n.w));
        float4 pe;
        pe.x = __expf(e4.x - m_n.x);
        pe.y = __expf(e4.y - m_n.y);
        pe.z = __expf(e4.z - m_n.z);
        pe.w = __expf(e4.w - m_n.w);
        ub[lane] = u_n << 7;  // fp16 row byte offset; pads point at phantom n
        pew[0] = pe.x;        // transposed stash: bank stride 64 -> 2-way, free
        pew[64] = pe.y;
        pew[128] = pe.z;
        pew[192] = pe.w;
        int s1 = s0 + 64;
        if (s1 < e3) {  // issue next chunk's loads before accumulate
            u_n = n;
            if (lane < e3 - s1) u_n = ssrc[s1 + lane];
            alu_n = *(const float4*)(als + 4 * (size_t)u_n);
            int e1 = s1 + lane;
            int nid1 = min(v0 + (e1 >= r1) + (e1 >= r2) + (e1 >= r3), vlast);
            ald_n = *(const float4*)(ald + 4 * (size_t)nid1);
            m_n = *(const float4*)(mvec + 4 * (size_t)nid1);
        }
        // same-wave LDS RAW (in-order DS unit), no barrier needed
        int lim = s0 + cnt;
        int hi0 = min(r1, lim);
        int lo1 = max(r1, s0), hi1 = min(r2, lim);
        int lo2 = max(r2, s0), hi2 = min(r3, lim);
        int lo3 = max(r3, s0);
        ACCUM(s0, hi0, acc0a, acc0b, zs0);
        ACCUM(lo1, hi1, acc1a, acc1b, zs1);
        ACCUM(lo2, hi2, acc2a, acc2b, zs2);
        ACCUM(lo3, lim, acc3a, acc3b, zs3);
        s0 = s1;
    }

    float bl = bias[lane];
    float o0 = fmaxf((acc0a + acc0b) / (1.f + zs0 + 1e-16f) + bl, 0.f);
    float o1 = fmaxf((acc1a + acc1b) / (1.f + zs1 + 1e-16f) + bl, 0.f);
    float o2 = fmaxf((acc2a + acc2b) / (1.f + zs2 + 1e-16f) + bl, 0.f);
    float o3 = fmaxf((acc3a + acc3b) / (1.f + zs3 + 1e-16f) + bl, 0.f);
    if (outw) {
        float ow = outw[lane];
        float ob = outb[0];
        float t0 = o0 * ow, t1 = o1 * ow, t2 = o2 * ow, t3 = o3 * ow;
#pragma unroll
        for (int d = 32; d; d >>= 1) {
            t0 += __shfl_down(t0, d, 64);
            t1 += __shfl_down(t1, d, 64);
            t2 += __shfl_down(t2, d, 64);
            t3 += __shfl_down(t3, d, 64);
        }
        if (lane == 0) {
            fout[v0] = t0 + ob;
            if (v0 + 1 < n) fout[v0 + 1] = t1 + ob;
            if (v0 + 2 < n) fout[v0 + 2] = t2 + ob;
            if (v0 + 3 < n) fout[v0 + 3] = t3 + ob;
        }
    } else {
        hout[((size_t)v0 << 6) + lane] = (half_t)o0;
        if (v0 + 1 < n) hout[((size_t)(v0 + 1) << 6) + lane] = (half_t)o1;
        if (v0 + 2 < n) hout[((size_t)(v0 + 2) << 6) + lane] = (half_t)o2;
        if (v0 + 3 < n) hout[((size_t)(v0 + 3) << 6) + lane] = (half_t)o3;
    }
}

extern "C" void kernel_launch(void* const* d_in, const int* in_sizes, int n_in,
                              void* d_out, int out_size, void* d_ws, size_t ws_size,
                              hipStream_t stream) {
    const float* x = (const float*)d_in[0];
    const int* ei = (const int*)d_in[1];
    const float* w[3] = {(const float*)d_in[2], (const float*)d_in[6], (const float*)d_in[10]};
    const float* as[3] = {(const float*)d_in[3], (const float*)d_in[7], (const float*)d_in[11]};
    const float* ad[3] = {(const float*)d_in[4], (const float*)d_in[8], (const float*)d_in[12]};
    const float* b[3] = {(const float*)d_in[5], (const float*)d_in[9], (const float*)d_in[13]};
    const float* outw = (const float*)d_in[14];
    const float* outb = (const float*)d_in[15];

    const int N = in_sizes[0] / 128;
    const int E = in_sizes[1] / 2;
    const int* src = ei;
    const int* dst = ei + E;
    const int NB = (N + 255) / 256;           // 391 <= NBMAX
    const int SB = (E + SCHUNK - 1) / SCHUNK; // 391
    const int GB128 = (N + 127) / 128;        // 782
    const int MG1 = (GB128 + 1) / 2;          // 391
    const int MG2 = GB128 - MG1;              // 391

    char* ws = (char*)d_ws;
    auto alloc = [&](size_t bytes) -> void* {
        void* p = (void*)ws;
        ws += (bytes + 255) & ~(size_t)255;
        return p;
    };
    int* bhist = (int*)alloc(NBMAX * 4);
    int* boffs = (int*)alloc((NBMAX + 1) * 4);
    int* bfill = (int*)alloc(NBMAX * 4);
    int* poffs = (int*)alloc((size_t)(N + 8) * 4);
    int* pend = (int*)alloc((size_t)N * 4);
    int* ssrc = (int*)alloc((size_t)(E + NBMAX * PADSLACK + 256) * 4);
    half_t* xh16 = (half_t*)alloc((size_t)(N + 1) * 64 * 2);  // +1: phantom zero row
    half_t* hbuf = (half_t*)alloc((size_t)N * 64 * 2);
    float* als = (float*)alloc((size_t)(N + 1) * 4 * 4);  // +1: phantom -1e30
    float* ald = (float*)alloc((size_t)N * 4 * 4);
    float* mvec = (float*)alloc((size_t)N * 4 * 4);
    unsigned short* p0h = (unsigned short*)alloc(8192 * 2);
    unsigned short* p0l = (unsigned short*)alloc(8192 * 2);
    unsigned short* p1h = (unsigned short*)alloc(4096 * 2);
    unsigned short* p1l = (unsigned short*)alloc(4096 * 2);
    unsigned short* p2h = (unsigned short*)alloc(4096 * 2);
    unsigned short* p2l = (unsigned short*)alloc(4096 * 2);
    // edata (E*4B = 6.4MB) aliases hbuf (N*128B = 12.8MB): hbuf stays dead
    // until agg0 writes it, which is after k_mix2 consumed edata.
    unsigned int* edata = (unsigned int*)hbuf;

    hipMemsetAsync(bhist, 0, NBMAX * 4, stream);  // stream-ordered; graph-capture-safe
    k_prep<<<9 + NBH, 256, 0, stream>>>(w[0], w[1], w[2], p0h, p0l, p1h, p1l, p2h, p2l,
                                        bhist, dst, E, als, xh16, N);
    k_bscan<<<1, 512, 0, stream>>>(bhist, boffs, bfill, NB, E);
    // CSR scatter || layer-0 GEMM first half (independent workloads)
    k_mix1<<<SB + MG1, 512, 0, stream>>>(src, dst, boffs, bfill, edata, E, SB,
                                         x, p0h, p0l, as[0], ad[0], xh16, als, ald, mvec, N);
    // CSR finalize || layer-0 GEMM second half
    k_mix2<<<NB + MG2, 512, 0, stream>>>(edata, boffs, poffs, pend, ssrc, N, NB, MG1,
                                         x, p0h, p0l, as[0], ad[0], xh16, als, ald, mvec);

    const int gblocks = (N + 63) / 64;
    const int ablocks = (N + 15) / 16;  // 4 nodes/wave, 4 waves/block

    k_agg<<<ablocks, 256, 0, stream>>>(xh16, als, ald, mvec, poffs, pend, ssrc, b[0], hbuf, nullptr, nullptr, nullptr, N);
    k_mgemm64<<<gblocks, 256, 0, stream>>>(hbuf, p1h, p1l, as[1], ad[1], xh16, als, ald, mvec, N);
    k_agg<<<ablocks, 256, 0, stream>>>(xh16, als, ald, mvec, poffs, pend, ssrc, b[1], hbuf, nullptr, nullptr, nullptr, N);
    k_mgemm64<<<gblocks, 256, 0, stream>>>(hbuf, p2h, p2l, as[2], ad[2], xh16, als, ald, mvec, N);
    k_agg<<<ablocks, 256, 0, stream>>>(xh16, als, ald, mvec, poffs, pend, ssrc, b[2], nullptr, outw, outb, (float*)d_out, N);
}